// Round 1
// baseline (4300.870 us; speedup 1.0000x reference)
//
#include <hip/hip_runtime.h>
#include <hip/hip_bf16.h>

#define NU_ 200000
#define NI_ 200000
#define D_ 128
#define H_ 128

// ---------------- degree / invdeg ----------------
__global__ void deg_kernel(const int* __restrict__ dst, int* __restrict__ deg, int E) {
    int e = blockIdx.x * blockDim.x + threadIdx.x;
    if (e < E) atomicAdd(&deg[dst[e]], 1);
}

__global__ void invdeg_kernel(const int* __restrict__ deg, float* __restrict__ inv, int N) {
    int i = blockIdx.x * blockDim.x + threadIdx.x;
    if (i < N) {
        int d = deg[i];
        inv[i] = 1.0f / (float)(d > 0 ? d : 1);
    }
}

// ---------------- scatter-mean (atomic) ----------------
// 32 lanes per edge, float4 per lane => 128 floats/edge
__global__ void scatter_mean(const float* __restrict__ x, const int* __restrict__ src,
                             const int* __restrict__ dst, const float* __restrict__ invdeg,
                             float* __restrict__ agg, int E) {
    long long gid = (long long)blockIdx.x * blockDim.x + threadIdx.x;
    int e = (int)(gid >> 5);
    int l = (int)(gid & 31);
    if (e >= E) return;
    int s = src[e];
    int d = dst[e];
    float sc = invdeg[d];
    const float4 v = *(const float4*)(x + (size_t)s * 128 + l * 4);
    float* p = agg + (size_t)d * 128 + l * 4;
    atomicAdd(p + 0, v.x * sc);
    atomicAdd(p + 1, v.y * sc);
    atomicAdd(p + 2, v.z * sc);
    atomicAdd(p + 3, v.w * sc);
}

// ---------------- fused dual-GEMM + bias (+leaky relu) ----------------
// out[N,128] = A1[N,128] @ W1[128,128] + A2[N,128] @ W2[128,128] + bias
// 128x128 tile per block, 256 threads, 8x8 acc per thread, BK=32.
#define BK 32
#define LDP 132   // padded leading dim (keeps 16B alignment, spreads banks)

__global__ __launch_bounds__(256)
void gemm_fused(const float* __restrict__ A1, const float* __restrict__ A2,
                const float* __restrict__ W1, const float* __restrict__ W2,
                const float* __restrict__ bias, float* __restrict__ out,
                int N, int lrelu) {
    __shared__ float At[BK][LDP];   // transposed A tile: At[k][row]
    __shared__ float Bt[BK][LDP];   // Bt[k][col]

    const int tid = threadIdx.x;
    const int tx = tid & 15;        // col group
    const int ty = tid >> 4;        // row group
    const int row0 = blockIdx.x * 128;

    float acc[8][8];
#pragma unroll
    for (int i = 0; i < 8; ++i)
#pragma unroll
        for (int j = 0; j < 8; ++j) acc[i][j] = 0.0f;

    const int sr = tid >> 3;        // 0..31  staging row base for A
    const int sq = tid & 7;         // 0..7   staging quad for A

    for (int pass = 0; pass < 2; ++pass) {
        const float* __restrict__ A = pass ? A2 : A1;
        const float* __restrict__ W = pass ? W2 : W1;
        for (int k0 = 0; k0 < 128; k0 += BK) {
            // ---- stage A (transpose): 128 rows x BK cols
#pragma unroll
            for (int i = 0; i < 4; ++i) {
                int rr = sr + i * 32;
                int row = row0 + rr;
                float4 v = make_float4(0.f, 0.f, 0.f, 0.f);
                if (row < N) v = *(const float4*)(A + (size_t)row * 128 + k0 + sq * 4);
                At[sq * 4 + 0][rr] = v.x;
                At[sq * 4 + 1][rr] = v.y;
                At[sq * 4 + 2][rr] = v.z;
                At[sq * 4 + 3][rr] = v.w;
            }
            // ---- stage B: BK rows x 128 cols
#pragma unroll
            for (int i = 0; i < 4; ++i) {
                int idx = tid + 256 * i;     // 0..1023
                int k = idx >> 5;            // 0..31
                int cq = idx & 31;           // col quad
                float4 w = *(const float4*)(W + (size_t)(k0 + k) * 128 + cq * 4);
                *(float4*)&Bt[k][cq * 4] = w;
            }
            __syncthreads();
#pragma unroll
            for (int kk = 0; kk < BK; ++kk) {
                float4 a0 = *(const float4*)&At[kk][ty * 8];
                float4 a1 = *(const float4*)&At[kk][ty * 8 + 4];
                float4 b0 = *(const float4*)&Bt[kk][tx * 8];
                float4 b1 = *(const float4*)&Bt[kk][tx * 8 + 4];
                float a[8] = {a0.x, a0.y, a0.z, a0.w, a1.x, a1.y, a1.z, a1.w};
                float b[8] = {b0.x, b0.y, b0.z, b0.w, b1.x, b1.y, b1.z, b1.w};
#pragma unroll
                for (int i = 0; i < 8; ++i)
#pragma unroll
                    for (int j = 0; j < 8; ++j) acc[i][j] += a[i] * b[j];
            }
            __syncthreads();
        }
    }

    // ---- epilogue
    float bb[8];
    {
        float4 b0 = *(const float4*)(bias + tx * 8);
        float4 b1 = *(const float4*)(bias + tx * 8 + 4);
        bb[0] = b0.x; bb[1] = b0.y; bb[2] = b0.z; bb[3] = b0.w;
        bb[4] = b1.x; bb[5] = b1.y; bb[6] = b1.z; bb[7] = b1.w;
    }
#pragma unroll
    for (int i = 0; i < 8; ++i) {
        int row = row0 + ty * 8 + i;
        if (row >= N) continue;
        float o[8];
#pragma unroll
        for (int j = 0; j < 8; ++j) {
            float v = acc[i][j] + bb[j];
            if (lrelu) v = v > 0.f ? v : 0.01f * v;
            o[j] = v;
        }
        float* p = out + (size_t)row * 128 + tx * 8;
        *(float4*)(p + 0) = make_float4(o[0], o[1], o[2], o[3]);
        *(float4*)(p + 4) = make_float4(o[4], o[5], o[6], o[7]);
    }
}

extern "C" void kernel_launch(void* const* d_in, const int* in_sizes, int n_in,
                              void* d_out, int out_size, void* d_ws, size_t ws_size,
                              hipStream_t stream) {
    const float* x_user     = (const float*)d_in[0];
    const float* x_item     = (const float*)d_in[1];
    const float* w1_self_uc = (const float*)d_in[2];
    const float* w1_neigh_uc= (const float*)d_in[3];
    const float* b1_uc      = (const float*)d_in[4];
    const float* w1_self_iu = (const float*)d_in[5];
    const float* w1_neigh_iu= (const float*)d_in[6];
    const float* b1_iu      = (const float*)d_in[7];
    const float* w2_self_uc = (const float*)d_in[8];
    const float* w2_neigh_uc= (const float*)d_in[9];
    const float* b2_uc      = (const float*)d_in[10];
    const float* w2_self_iu = (const float*)d_in[11];
    const float* w2_neigh_iu= (const float*)d_in[12];
    const float* b2_iu      = (const float*)d_in[13];
    const int* src_uc = (const int*)d_in[14];
    const int* dst_uc = (const int*)d_in[15];
    const int* src_iu = (const int*)d_in[16];
    const int* dst_iu = (const int*)d_in[17];

    const int NU = in_sizes[0] / D_;
    const int NI = in_sizes[1] / D_;
    const int E  = in_sizes[14];

    float* out_user = (float*)d_out;                       // h2_user
    float* out_item = (float*)d_out + (size_t)NU * H_;     // h2_item

    // workspace layout
    char* ws = (char*)d_ws;
    const size_t FEAT_BYTES = (size_t)200000 * 128 * sizeof(float); // 102.4 MB
    float* agg     = (float*)ws;                 ws += FEAT_BYTES;
    float* h1_item = (float*)ws;                 ws += FEAT_BYTES;
    float* h1_user = (float*)ws;                 ws += FEAT_BYTES;
    int*   deg_uc  = (int*)ws;                   ws += (size_t)200000 * sizeof(int);
    int*   deg_iu  = (int*)ws;                   ws += (size_t)200000 * sizeof(int);
    float* inv_uc  = (float*)ws;                 ws += (size_t)200000 * sizeof(float);
    float* inv_iu  = (float*)ws;                 ws += (size_t)200000 * sizeof(float);

    const int TPB = 256;
    const int degBlocks = (E + TPB - 1) / TPB;
    const int invBlocksI = (NI + TPB - 1) / TPB;
    const int invBlocksU = (NU + TPB - 1) / TPB;
    const long long scatterThreads = (long long)E * 32;
    const int scatterBlocks = (int)((scatterThreads + TPB - 1) / TPB);
    const int gemmBlocksI = (NI + 127) / 128;
    const int gemmBlocksU = (NU + 127) / 128;

    // degrees (shared by both layers)
    hipMemsetAsync(deg_uc, 0, (size_t)NI * sizeof(int), stream);
    hipMemsetAsync(deg_iu, 0, (size_t)NU * sizeof(int), stream);
    deg_kernel<<<degBlocks, TPB, 0, stream>>>(dst_uc, deg_uc, E);
    deg_kernel<<<degBlocks, TPB, 0, stream>>>(dst_iu, deg_iu, E);
    invdeg_kernel<<<invBlocksI, TPB, 0, stream>>>(deg_uc, inv_uc, NI);
    invdeg_kernel<<<invBlocksU, TPB, 0, stream>>>(deg_iu, inv_iu, NU);

    // ---- layer 1, item side (relation uc: user -> item)
    hipMemsetAsync(agg, 0, FEAT_BYTES, stream);
    scatter_mean<<<scatterBlocks, TPB, 0, stream>>>(x_user, src_uc, dst_uc, inv_uc, agg, E);
    gemm_fused<<<gemmBlocksI, TPB, 0, stream>>>(x_item, agg, w1_self_uc, w1_neigh_uc,
                                                b1_uc, h1_item, NI, 1);
    // ---- layer 1, user side (relation iu: item -> user)
    hipMemsetAsync(agg, 0, FEAT_BYTES, stream);
    scatter_mean<<<scatterBlocks, TPB, 0, stream>>>(x_item, src_iu, dst_iu, inv_iu, agg, E);
    gemm_fused<<<gemmBlocksU, TPB, 0, stream>>>(x_user, agg, w1_self_iu, w1_neigh_iu,
                                                b1_iu, h1_user, NU, 1);
    // ---- layer 2, item side
    hipMemsetAsync(agg, 0, FEAT_BYTES, stream);
    scatter_mean<<<scatterBlocks, TPB, 0, stream>>>(h1_user, src_uc, dst_uc, inv_uc, agg, E);
    gemm_fused<<<gemmBlocksI, TPB, 0, stream>>>(h1_item, agg, w2_self_uc, w2_neigh_uc,
                                                b2_uc, out_item, NI, 0);
    // ---- layer 2, user side
    hipMemsetAsync(agg, 0, FEAT_BYTES, stream);
    scatter_mean<<<scatterBlocks, TPB, 0, stream>>>(h1_item, src_iu, dst_iu, inv_iu, agg, E);
    gemm_fused<<<gemmBlocksU, TPB, 0, stream>>>(h1_user, agg, w2_self_iu, w2_neigh_iu,
                                                b2_iu, out_user, NU, 0);
}

// Round 2
// 1355.171 us; speedup vs baseline: 3.1737x; 3.1737x over previous
//
#include <hip/hip_runtime.h>
#include <hip/hip_bf16.h>

#define D_ 128
#define H_ 128

// ---------------- degree ----------------
__global__ void deg_kernel(const int* __restrict__ dst, int* __restrict__ deg, int E) {
    int e = blockIdx.x * blockDim.x + threadIdx.x;
    if (e < E) atomicAdd(&deg[dst[e]], 1);
}

// ---------------- exclusive scan (3-kernel) ----------------
__global__ __launch_bounds__(256)
void scan1(const int* __restrict__ deg, int* __restrict__ rp,
           int* __restrict__ partials, int N) {
    int tid = threadIdx.x;
    int i = blockIdx.x * 256 + tid;
    int v = (i < N) ? deg[i] : 0;
    int lane = tid & 63, wid = tid >> 6;
    int x = v;
#pragma unroll
    for (int off = 1; off < 64; off <<= 1) {
        int y = __shfl_up(x, off, 64);
        if (lane >= off) x += y;
    }
    __shared__ int wsum[5];
    if (lane == 63) wsum[wid] = x;
    __syncthreads();
    if (tid == 0) {
        int a = wsum[0], b = wsum[1], c = wsum[2], d = wsum[3];
        wsum[0] = 0; wsum[1] = a; wsum[2] = a + b; wsum[3] = a + b + c;
        wsum[4] = a + b + c + d;
    }
    __syncthreads();
    if (i < N) rp[i] = wsum[wid] + x - v;           // exclusive
    if (tid == 0) partials[blockIdx.x] = wsum[4];   // block total
}

__global__ __launch_bounds__(1024)
void scan2(int* __restrict__ partials, int B) {
    __shared__ int buf[1024];
    int t = threadIdx.x;
    int v = (t < B) ? partials[t] : 0;
    buf[t] = v;
    __syncthreads();
    for (int off = 1; off < 1024; off <<= 1) {
        int add = (t >= off) ? buf[t - off] : 0;
        __syncthreads();
        buf[t] += add;
        __syncthreads();
    }
    if (t < B) partials[t] = buf[t] - v;            // exclusive
}

__global__ __launch_bounds__(256)
void scan3(int* __restrict__ rp, const int* __restrict__ partials, int N, int E) {
    int i = blockIdx.x * 256 + threadIdx.x;
    if (i < N) rp[i] += partials[blockIdx.x];
    if (i == 0) rp[N] = E;
}

// ---------------- CSR fill ----------------
__global__ void fill_csr(const int* __restrict__ src, const int* __restrict__ dst,
                         const int* __restrict__ rp, int* __restrict__ cursor,
                         int* __restrict__ col, int E) {
    int e = blockIdx.x * blockDim.x + threadIdx.x;
    if (e < E) {
        int d = dst[e];
        int slot = rp[d] + atomicAdd(&cursor[d], 1);
        col[slot] = src[e];
    }
}

// ---------------- gather-mean: one wave per dst node ----------------
__global__ __launch_bounds__(256)
void gather_mean(const float* __restrict__ x, const int* __restrict__ rp,
                 const int* __restrict__ col, float* __restrict__ out, int N) {
    long long gid = (long long)blockIdx.x * blockDim.x + threadIdx.x;
    int node = (int)(gid >> 6);
    int lane = (int)(gid & 63);
    if (node >= N) return;
    int beg = rp[node], end = rp[node + 1];
    float ax = 0.f, ay = 0.f;
    for (int e = beg; e < end; ++e) {
        int s = col[e];
        const float2 v = *(const float2*)(x + (size_t)s * 128 + lane * 2);
        ax += v.x; ay += v.y;
    }
    int dg = end - beg;
    float inv = 1.0f / (float)(dg > 0 ? dg : 1);
    *(float2*)(out + (size_t)node * 128 + lane * 2) = make_float2(ax * inv, ay * inv);
}

// ---------------- fused dual-GEMM + bias (+leaky relu) ----------------
// out[N,128] = A1[N,128] @ W1 + A2[N,128] @ W2 + bias ; in-place (out==A1) safe:
// each block writes only its own A1 rows, after all its reads of them.
#define BK 32
#define LDP 132

__global__ __launch_bounds__(256)
void gemm_fused(const float* __restrict__ A1, const float* __restrict__ A2,
                const float* __restrict__ W1, const float* __restrict__ W2,
                const float* __restrict__ bias, float* __restrict__ out,
                int N, int lrelu) {
    __shared__ float At[BK][LDP];
    __shared__ float Bt[BK][LDP];

    const int tid = threadIdx.x;
    const int tx = tid & 15;
    const int ty = tid >> 4;
    const int row0 = blockIdx.x * 128;

    float acc[8][8];
#pragma unroll
    for (int i = 0; i < 8; ++i)
#pragma unroll
        for (int j = 0; j < 8; ++j) acc[i][j] = 0.0f;

    const int sr = tid >> 3;
    const int sq = tid & 7;

    for (int pass = 0; pass < 2; ++pass) {
        const float* __restrict__ A = pass ? A2 : A1;
        const float* __restrict__ W = pass ? W2 : W1;
        for (int k0 = 0; k0 < 128; k0 += BK) {
#pragma unroll
            for (int i = 0; i < 4; ++i) {
                int rr = sr + i * 32;
                int row = row0 + rr;
                float4 v = make_float4(0.f, 0.f, 0.f, 0.f);
                if (row < N) v = *(const float4*)(A + (size_t)row * 128 + k0 + sq * 4);
                At[sq * 4 + 0][rr] = v.x;
                At[sq * 4 + 1][rr] = v.y;
                At[sq * 4 + 2][rr] = v.z;
                At[sq * 4 + 3][rr] = v.w;
            }
#pragma unroll
            for (int i = 0; i < 4; ++i) {
                int idx = tid + 256 * i;
                int k = idx >> 5;
                int cq = idx & 31;
                float4 w = *(const float4*)(W + (size_t)(k0 + k) * 128 + cq * 4);
                *(float4*)&Bt[k][cq * 4] = w;
            }
            __syncthreads();
#pragma unroll
            for (int kk = 0; kk < BK; ++kk) {
                float4 a0 = *(const float4*)&At[kk][ty * 8];
                float4 a1 = *(const float4*)&At[kk][ty * 8 + 4];
                float4 b0 = *(const float4*)&Bt[kk][tx * 8];
                float4 b1 = *(const float4*)&Bt[kk][tx * 8 + 4];
                float a[8] = {a0.x, a0.y, a0.z, a0.w, a1.x, a1.y, a1.z, a1.w};
                float b[8] = {b0.x, b0.y, b0.z, b0.w, b1.x, b1.y, b1.z, b1.w};
#pragma unroll
                for (int i = 0; i < 8; ++i)
#pragma unroll
                    for (int j = 0; j < 8; ++j) acc[i][j] += a[i] * b[j];
            }
            __syncthreads();
        }
    }

    float bb[8];
    {
        float4 b0 = *(const float4*)(bias + tx * 8);
        float4 b1 = *(const float4*)(bias + tx * 8 + 4);
        bb[0] = b0.x; bb[1] = b0.y; bb[2] = b0.z; bb[3] = b0.w;
        bb[4] = b1.x; bb[5] = b1.y; bb[6] = b1.z; bb[7] = b1.w;
    }
#pragma unroll
    for (int i = 0; i < 8; ++i) {
        int row = row0 + ty * 8 + i;
        if (row >= N) continue;
        float o[8];
#pragma unroll
        for (int j = 0; j < 8; ++j) {
            float v = acc[i][j] + bb[j];
            if (lrelu) v = v > 0.f ? v : 0.01f * v;
            o[j] = v;
        }
        float* p = out + (size_t)row * 128 + tx * 8;
        *(float4*)(p + 0) = make_float4(o[0], o[1], o[2], o[3]);
        *(float4*)(p + 4) = make_float4(o[4], o[5], o[6], o[7]);
    }
}

extern "C" void kernel_launch(void* const* d_in, const int* in_sizes, int n_in,
                              void* d_out, int out_size, void* d_ws, size_t ws_size,
                              hipStream_t stream) {
    const float* x_user     = (const float*)d_in[0];
    const float* x_item     = (const float*)d_in[1];
    const float* w1_self_uc = (const float*)d_in[2];
    const float* w1_neigh_uc= (const float*)d_in[3];
    const float* b1_uc      = (const float*)d_in[4];
    const float* w1_self_iu = (const float*)d_in[5];
    const float* w1_neigh_iu= (const float*)d_in[6];
    const float* b1_iu      = (const float*)d_in[7];
    const float* w2_self_uc = (const float*)d_in[8];
    const float* w2_neigh_uc= (const float*)d_in[9];
    const float* b2_uc      = (const float*)d_in[10];
    const float* w2_self_iu = (const float*)d_in[11];
    const float* w2_neigh_iu= (const float*)d_in[12];
    const float* b2_iu      = (const float*)d_in[13];
    const int* src_uc = (const int*)d_in[14];
    const int* dst_uc = (const int*)d_in[15];
    const int* src_iu = (const int*)d_in[16];
    const int* dst_iu = (const int*)d_in[17];

    const int NU = in_sizes[0] / D_;
    const int NI = in_sizes[1] / D_;
    const int E  = in_sizes[14];

    float* out_user = (float*)d_out;                   // doubles as h1_user scratch
    float* out_item = (float*)d_out + (size_t)NU * H_; // doubles as h1_item scratch

    // workspace layout
    char* ws = (char*)d_ws;
    const size_t FEAT_BYTES = (size_t)200000 * 128 * sizeof(float); // 102.4 MB
    float* agg_i  = (float*)ws;  ws += FEAT_BYTES;
    float* agg_u  = (float*)ws;  ws += FEAT_BYTES;
    int* rp_uc    = (int*)ws;    ws += (size_t)(NI + 1) * sizeof(int);
    int* rp_iu    = (int*)ws;    ws += (size_t)(NU + 1) * sizeof(int);
    int* col_uc   = (int*)ws;    ws += (size_t)E * sizeof(int);
    int* col_iu   = (int*)ws;    ws += (size_t)E * sizeof(int);
    int* deg      = (int*)ws;    ws += (size_t)200000 * sizeof(int);  // reused as cursor
    int* partials = (int*)ws;    ws += (size_t)1024 * sizeof(int);

    const int TPB = 256;
    const int eBlocks  = (E + TPB - 1) / TPB;
    const int sBlocksI = (NI + 255) / 256;
    const int sBlocksU = (NU + 255) / 256;
    const int gBlocksI = (int)(((long long)NI * 64 + TPB - 1) / TPB);
    const int gBlocksU = (int)(((long long)NU * 64 + TPB - 1) / TPB);
    const int mBlocksI = (NI + 127) / 128;
    const int mBlocksU = (NU + 127) / 128;

    // ---- CSR for relation uc (dst = item) ----
    hipMemsetAsync(deg, 0, (size_t)NI * sizeof(int), stream);
    deg_kernel<<<eBlocks, TPB, 0, stream>>>(dst_uc, deg, E);
    scan1<<<sBlocksI, 256, 0, stream>>>(deg, rp_uc, partials, NI);
    scan2<<<1, 1024, 0, stream>>>(partials, sBlocksI);
    scan3<<<sBlocksI, 256, 0, stream>>>(rp_uc, partials, NI, E);
    hipMemsetAsync(deg, 0, (size_t)NI * sizeof(int), stream);
    fill_csr<<<eBlocks, TPB, 0, stream>>>(src_uc, dst_uc, rp_uc, deg, col_uc, E);

    // ---- CSR for relation iu (dst = user) ----
    hipMemsetAsync(deg, 0, (size_t)NU * sizeof(int), stream);
    deg_kernel<<<eBlocks, TPB, 0, stream>>>(dst_iu, deg, E);
    scan1<<<sBlocksU, 256, 0, stream>>>(deg, rp_iu, partials, NU);
    scan2<<<1, 1024, 0, stream>>>(partials, sBlocksU);
    scan3<<<sBlocksU, 256, 0, stream>>>(rp_iu, partials, NU, E);
    hipMemsetAsync(deg, 0, (size_t)NU * sizeof(int), stream);
    fill_csr<<<eBlocks, TPB, 0, stream>>>(src_iu, dst_iu, rp_iu, deg, col_iu, E);

    // ---- layer 1 ----
    gather_mean<<<gBlocksI, TPB, 0, stream>>>(x_user, rp_uc, col_uc, agg_i, NI);
    gemm_fused<<<mBlocksI, TPB, 0, stream>>>(x_item, agg_i, w1_self_uc, w1_neigh_uc,
                                             b1_uc, out_item /*h1_item*/, NI, 1);
    gather_mean<<<gBlocksU, TPB, 0, stream>>>(x_item, rp_iu, col_iu, agg_u, NU);
    gemm_fused<<<mBlocksU, TPB, 0, stream>>>(x_user, agg_u, w1_self_iu, w1_neigh_iu,
                                             b1_iu, out_user /*h1_user*/, NU, 1);

    // ---- layer 2: both gathers first (they consume h1 from d_out), then in-place GEMMs
    gather_mean<<<gBlocksI, TPB, 0, stream>>>(out_user /*h1_user*/, rp_uc, col_uc, agg_i, NI);
    gather_mean<<<gBlocksU, TPB, 0, stream>>>(out_item /*h1_item*/, rp_iu, col_iu, agg_u, NU);
    gemm_fused<<<mBlocksI, TPB, 0, stream>>>(out_item, agg_i, w2_self_uc, w2_neigh_uc,
                                             b2_uc, out_item, NI, 0);
    gemm_fused<<<mBlocksU, TPB, 0, stream>>>(out_user, agg_u, w2_self_iu, w2_neigh_iu,
                                             b2_iu, out_user, NU, 0);
}

// Round 3
// 866.169 us; speedup vs baseline: 4.9654x; 1.5646x over previous
//
#include <hip/hip_runtime.h>
#include <hip/hip_bf16.h>

#define D_ 128
#define H_ 128

typedef __attribute__((ext_vector_type(8))) short s8b;   // 8 bf16
typedef __attribute__((ext_vector_type(4))) float f4;    // MFMA acc

union U4 { uint u[4]; s8b v; uint4 q; };

// ---------------- degree ----------------
__global__ void deg_kernel(const int* __restrict__ dst, int* __restrict__ deg, int E) {
    int e = blockIdx.x * blockDim.x + threadIdx.x;
    if (e < E) atomicAdd(&deg[dst[e]], 1);
}

// ---------------- exclusive scan (3-kernel) ----------------
__global__ __launch_bounds__(256)
void scan1(const int* __restrict__ deg, int* __restrict__ rp,
           int* __restrict__ partials, int N) {
    int tid = threadIdx.x;
    int i = blockIdx.x * 256 + tid;
    int v = (i < N) ? deg[i] : 0;
    int lane = tid & 63, wid = tid >> 6;
    int x = v;
#pragma unroll
    for (int off = 1; off < 64; off <<= 1) {
        int y = __shfl_up(x, off, 64);
        if (lane >= off) x += y;
    }
    __shared__ int wsum[5];
    if (lane == 63) wsum[wid] = x;
    __syncthreads();
    if (tid == 0) {
        int a = wsum[0], b = wsum[1], c = wsum[2], d = wsum[3];
        wsum[0] = 0; wsum[1] = a; wsum[2] = a + b; wsum[3] = a + b + c;
        wsum[4] = a + b + c + d;
    }
    __syncthreads();
    if (i < N) rp[i] = wsum[wid] + x - v;
    if (tid == 0) partials[blockIdx.x] = wsum[4];
}

__global__ __launch_bounds__(1024)
void scan2(int* __restrict__ partials, int B) {
    __shared__ int buf[1024];
    int t = threadIdx.x;
    int v = (t < B) ? partials[t] : 0;
    buf[t] = v;
    __syncthreads();
    for (int off = 1; off < 1024; off <<= 1) {
        int add = (t >= off) ? buf[t - off] : 0;
        __syncthreads();
        buf[t] += add;
        __syncthreads();
    }
    if (t < B) partials[t] = buf[t] - v;
}

__global__ __launch_bounds__(256)
void scan3(int* __restrict__ rp, const int* __restrict__ partials, int N, int E) {
    int i = blockIdx.x * 256 + threadIdx.x;
    if (i < N) rp[i] += partials[blockIdx.x];
    if (i == 0) rp[N] = E;
}

// ---------------- CSR fill ----------------
__global__ void fill_csr(const int* __restrict__ src, const int* __restrict__ dst,
                         const int* __restrict__ rp, int* __restrict__ cursor,
                         int* __restrict__ col, int E) {
    int e = blockIdx.x * blockDim.x + threadIdx.x;
    if (e < E) {
        int d = dst[e];
        int slot = rp[d] + atomicAdd(&cursor[d], 1);
        col[slot] = src[e];
    }
}

// ---------------- gather-mean: one wave per dst node ----------------
__global__ __launch_bounds__(256)
void gather_mean(const float* __restrict__ x, const int* __restrict__ rp,
                 const int* __restrict__ col, float* __restrict__ out, int N) {
    long long gid = (long long)blockIdx.x * blockDim.x + threadIdx.x;
    int node = (int)(gid >> 6);
    int lane = (int)(gid & 63);
    if (node >= N) return;
    int beg = rp[node], end = rp[node + 1];
    float ax = 0.f, ay = 0.f;
    for (int e = beg; e < end; ++e) {
        int s = col[e];
        const float2 v = *(const float2*)(x + (size_t)s * 128 + lane * 2);
        ax += v.x; ay += v.y;
    }
    int dg = end - beg;
    float inv = 1.0f / (float)(dg > 0 ? dg : 1);
    *(float2*)(out + (size_t)node * 128 + lane * 2) = make_float2(ax * inv, ay * inv);
}

// ---------------- weight prep: transpose + bf16 h/l split ----------------
// For each config g: WT[g] is [col 0..127][kv 0..255] bf16 where kv<128 -> W_self[kv][col],
// kv>=128 -> W_neigh[kv-128][col]. High part = truncation, low part = RNE(residual).
__global__ __launch_bounds__(256)
void prep_weights(const float* __restrict__ s0, const float* __restrict__ n0,
                  const float* __restrict__ s1, const float* __restrict__ n1,
                  const float* __restrict__ s2, const float* __restrict__ n2,
                  const float* __restrict__ s3, const float* __restrict__ n3,
                  ushort* __restrict__ WTH, ushort* __restrict__ WTL) {
    int g = blockIdx.y;
    int t = blockIdx.x * 256 + threadIdx.x;   // 0..4095
    int c = t & 127;
    int oct = t >> 7;                          // 0..31 (8 kv each)
    const float* self  = g == 0 ? s0 : g == 1 ? s1 : g == 2 ? s2 : s3;
    const float* neigh = g == 0 ? n0 : g == 1 ? n1 : g == 2 ? n2 : n3;
    uint hd[4], ld_[4];
#pragma unroll
    for (int p = 0; p < 4; ++p) {
        uint hpair = 0, lpair = 0;
#pragma unroll
        for (int q = 0; q < 2; ++q) {
            int kv = oct * 8 + p * 2 + q;
            const float* Wsrc = kv < 128 ? self : neigh;
            float f = Wsrc[(size_t)(kv & 127) * 128 + c];
            uint u = __float_as_uint(f);
            uint h = u >> 16;                            // truncate
            float r = f - __uint_as_float(u & 0xffff0000u);
            uint v = __float_as_uint(r);
            uint l = (v + 0x7fffu + ((v >> 16) & 1u)) >> 16;  // RNE
            hpair |= h << (16 * q);
            lpair |= l << (16 * q);
        }
        hd[p] = hpair; ld_[p] = lpair;
    }
    size_t base = ((size_t)g * 128 + c) * 256 + oct * 8;
    *(uint4*)(WTH + base) = make_uint4(hd[0], hd[1], hd[2], hd[3]);
    *(uint4*)(WTL + base) = make_uint4(ld_[0], ld_[1], ld_[2], ld_[3]);
}

// ---------------- MFMA GEMM: out[N,128] = A1@W_self + A2@W_neigh + bias ----------------
// Virtual K = 256 (ks 0..3 -> A1/self, 4..7 -> A2/neigh). Compensated bf16:
// acc = Ah@Wh + Al@Wh + Ah@Wl. 128x128 tile, 4 waves of 64x64, 16x16x32 MFMA.
__global__ __launch_bounds__(256)
void gemm_mfma(const float* __restrict__ A1, const float* __restrict__ A2,
               const ushort* __restrict__ WTh, const ushort* __restrict__ WTl,
               const float* __restrict__ bias, float* __restrict__ out,
               int N, int lrelu) {
    __shared__ s8b ldsAh[512];
    __shared__ s8b ldsAl[512];
    __shared__ s8b ldsWh[512];
    __shared__ s8b ldsWl[512];

    const int t = threadIdx.x;
    const int row0 = blockIdx.x * 128;
    const int lane = t & 63, w = t >> 6;
    const int mrow0 = (w & 1) * 64, ncol0 = (w >> 1) * 64;
    const int fr = lane & 15, hi = lane >> 4;

    // accumulators init with bias
    f4 acc[4][4];
    float bv[4];
#pragma unroll
    for (int n = 0; n < 4; ++n) bv[n] = bias[ncol0 + n * 16 + fr];
#pragma unroll
    for (int m = 0; m < 4; ++m)
#pragma unroll
        for (int n = 0; n < 4; ++n) acc[m][n] = (f4){bv[n], bv[n], bv[n], bv[n]};

    const int sr = t >> 1, half = t & 1;       // staging: row, k-half
    const int grow = row0 + sr;
    const int swz = (sr >> 1) & 3;             // same formula for A-row and W-col

    // precompute frag slot indices
    int aslot[4], wslot[4];
#pragma unroll
    for (int m = 0; m < 4; ++m) {
        int r = mrow0 + m * 16 + fr;
        aslot[m] = r * 4 + (hi ^ ((r >> 1) & 3));
    }
#pragma unroll
    for (int n = 0; n < 4; ++n) {
        int c = ncol0 + n * 16 + fr;
        wslot[n] = c * 4 + (hi ^ ((c >> 1) & 3));
    }

    for (int ks = 0; ks < 8; ++ks) {
        // ---- stage A: 128 rows x 32 k, fp32 -> bf16 h/l
        const float* __restrict__ As = (ks < 4) ? A1 : A2;
        const int k0 = (ks & 3) * 32 + half * 16;
        float e[16];
        if (grow < N) {
            const float4* p = (const float4*)(As + (size_t)grow * 128 + k0);
            float4 q0 = p[0], q1 = p[1], q2 = p[2], q3 = p[3];
            e[0] = q0.x; e[1] = q0.y; e[2] = q0.z; e[3] = q0.w;
            e[4] = q1.x; e[5] = q1.y; e[6] = q1.z; e[7] = q1.w;
            e[8] = q2.x; e[9] = q2.y; e[10] = q2.z; e[11] = q2.w;
            e[12] = q3.x; e[13] = q3.y; e[14] = q3.z; e[15] = q3.w;
        } else {
#pragma unroll
            for (int i = 0; i < 16; ++i) e[i] = 0.f;
        }
        uint hd[8], ld_[8];
#pragma unroll
        for (int p = 0; p < 8; ++p) {
            uint u0 = __float_as_uint(e[2 * p]);
            uint u1 = __float_as_uint(e[2 * p + 1]);
            hd[p] = (u0 >> 16) | (u1 & 0xffff0000u);
            float r0 = e[2 * p] - __uint_as_float(u0 & 0xffff0000u);
            float r1 = e[2 * p + 1] - __uint_as_float(u1 & 0xffff0000u);
            uint v0 = __float_as_uint(r0), v1 = __float_as_uint(r1);
            uint l0 = (v0 + 0x7fffu + ((v0 >> 16) & 1u)) >> 16;
            uint l1 = (v1 + 0x7fffu + ((v1 >> 16) & 1u)) >> 16;
            ld_[p] = l0 | (l1 << 16);
        }
        {
            U4 a0; a0.u[0] = hd[0]; a0.u[1] = hd[1]; a0.u[2] = hd[2]; a0.u[3] = hd[3];
            U4 a1; a1.u[0] = hd[4]; a1.u[1] = hd[5]; a1.u[2] = hd[6]; a1.u[3] = hd[7];
            U4 b0; b0.u[0] = ld_[0]; b0.u[1] = ld_[1]; b0.u[2] = ld_[2]; b0.u[3] = ld_[3];
            U4 b1; b1.u[0] = ld_[4]; b1.u[1] = ld_[5]; b1.u[2] = ld_[6]; b1.u[3] = ld_[7];
            int h0 = half * 2, h1 = half * 2 + 1;
            ldsAh[sr * 4 + (h0 ^ swz)] = a0.v;
            ldsAh[sr * 4 + (h1 ^ swz)] = a1.v;
            ldsAl[sr * 4 + (h0 ^ swz)] = b0.v;
            ldsAl[sr * 4 + (h1 ^ swz)] = b1.v;
        }
        // ---- stage W: pre-split/transposed global -> LDS (swizzled)
        {
            size_t wbase = (size_t)sr * 256 + ks * 32 + half * 16;
            U4 wh0, wh1, wl0, wl1;
            wh0.q = *(const uint4*)(WTh + wbase);
            wh1.q = *(const uint4*)(WTh + wbase + 8);
            wl0.q = *(const uint4*)(WTl + wbase);
            wl1.q = *(const uint4*)(WTl + wbase + 8);
            int h0 = half * 2, h1 = half * 2 + 1;
            ldsWh[sr * 4 + (h0 ^ swz)] = wh0.v;
            ldsWh[sr * 4 + (h1 ^ swz)] = wh1.v;
            ldsWl[sr * 4 + (h0 ^ swz)] = wl0.v;
            ldsWl[sr * 4 + (h1 ^ swz)] = wl1.v;
        }
        __syncthreads();

        // ---- compute: 48 MFMAs per wave
        s8b ah[4], al[4];
#pragma unroll
        for (int m = 0; m < 4; ++m) { ah[m] = ldsAh[aslot[m]]; al[m] = ldsAl[aslot[m]]; }
#pragma unroll
        for (int n = 0; n < 4; ++n) {
            s8b wh = ldsWh[wslot[n]];
            s8b wl = ldsWl[wslot[n]];
#pragma unroll
            for (int m = 0; m < 4; ++m) {
                acc[m][n] = __builtin_amdgcn_mfma_f32_16x16x32_bf16(ah[m], wh, acc[m][n], 0, 0, 0);
                acc[m][n] = __builtin_amdgcn_mfma_f32_16x16x32_bf16(al[m], wh, acc[m][n], 0, 0, 0);
                acc[m][n] = __builtin_amdgcn_mfma_f32_16x16x32_bf16(ah[m], wl, acc[m][n], 0, 0, 0);
            }
        }
        __syncthreads();
    }

    // ---- epilogue
#pragma unroll
    for (int m = 0; m < 4; ++m) {
#pragma unroll
        for (int r = 0; r < 4; ++r) {
            int row = row0 + mrow0 + m * 16 + hi * 4 + r;
            if (row >= N) continue;
#pragma unroll
            for (int n = 0; n < 4; ++n) {
                float v = acc[m][n][r];
                if (lrelu) v = v > 0.f ? v : 0.01f * v;
                out[(size_t)row * 128 + ncol0 + n * 16 + fr] = v;
            }
        }
    }
}

extern "C" void kernel_launch(void* const* d_in, const int* in_sizes, int n_in,
                              void* d_out, int out_size, void* d_ws, size_t ws_size,
                              hipStream_t stream) {
    const float* x_user     = (const float*)d_in[0];
    const float* x_item     = (const float*)d_in[1];
    const float* w1_self_uc = (const float*)d_in[2];
    const float* w1_neigh_uc= (const float*)d_in[3];
    const float* b1_uc      = (const float*)d_in[4];
    const float* w1_self_iu = (const float*)d_in[5];
    const float* w1_neigh_iu= (const float*)d_in[6];
    const float* b1_iu      = (const float*)d_in[7];
    const float* w2_self_uc = (const float*)d_in[8];
    const float* w2_neigh_uc= (const float*)d_in[9];
    const float* b2_uc      = (const float*)d_in[10];
    const float* w2_self_iu = (const float*)d_in[11];
    const float* w2_neigh_iu= (const float*)d_in[12];
    const float* b2_iu      = (const float*)d_in[13];
    const int* src_uc = (const int*)d_in[14];
    const int* dst_uc = (const int*)d_in[15];
    const int* src_iu = (const int*)d_in[16];
    const int* dst_iu = (const int*)d_in[17];

    const int NU = in_sizes[0] / D_;
    const int NI = in_sizes[1] / D_;
    const int E  = in_sizes[14];

    float* out_user = (float*)d_out;                   // doubles as h1_user scratch
    float* out_item = (float*)d_out + (size_t)NU * H_; // doubles as h1_item scratch

    // workspace layout (16B-aligned chunks first)
    char* ws = (char*)d_ws;
    const size_t FEAT_BYTES = (size_t)200000 * 128 * sizeof(float); // 102.4 MB
    float* agg_i  = (float*)ws;  ws += FEAT_BYTES;
    float* agg_u  = (float*)ws;  ws += FEAT_BYTES;
    ushort* WTH   = (ushort*)ws; ws += (size_t)4 * 128 * 256 * sizeof(ushort); // 256KB
    ushort* WTL   = (ushort*)ws; ws += (size_t)4 * 128 * 256 * sizeof(ushort);
    int* rp_uc    = (int*)ws;    ws += (size_t)(NI + 1) * sizeof(int);
    int* rp_iu    = (int*)ws;    ws += (size_t)(NU + 1) * sizeof(int);
    int* col_uc   = (int*)ws;    ws += (size_t)E * sizeof(int);
    int* col_iu   = (int*)ws;    ws += (size_t)E * sizeof(int);
    int* deg      = (int*)ws;    ws += (size_t)200000 * sizeof(int);
    int* partials = (int*)ws;    ws += (size_t)1024 * sizeof(int);

    const int TPB = 256;
    const int eBlocks  = (E + TPB - 1) / TPB;
    const int sBlocksI = (NI + 255) / 256;
    const int sBlocksU = (NU + 255) / 256;
    const int gBlocksI = (int)(((long long)NI * 64 + TPB - 1) / TPB);
    const int gBlocksU = (int)(((long long)NU * 64 + TPB - 1) / TPB);
    const int mBlocksI = (NI + 127) / 128;
    const int mBlocksU = (NU + 127) / 128;

    // per-config weight bases: g0=l1_uc, g1=l1_iu, g2=l2_uc, g3=l2_iu
    const size_t WSTRIDE = (size_t)128 * 256;

    // ---- weight prep (independent of CSR) ----
    prep_weights<<<dim3(16, 4), 256, 0, stream>>>(
        w1_self_uc, w1_neigh_uc, w1_self_iu, w1_neigh_iu,
        w2_self_uc, w2_neigh_uc, w2_self_iu, w2_neigh_iu, WTH, WTL);

    // ---- CSR for relation uc (dst = item) ----
    hipMemsetAsync(deg, 0, (size_t)NI * sizeof(int), stream);
    deg_kernel<<<eBlocks, TPB, 0, stream>>>(dst_uc, deg, E);
    scan1<<<sBlocksI, 256, 0, stream>>>(deg, rp_uc, partials, NI);
    scan2<<<1, 1024, 0, stream>>>(partials, sBlocksI);
    scan3<<<sBlocksI, 256, 0, stream>>>(rp_uc, partials, NI, E);
    hipMemsetAsync(deg, 0, (size_t)NI * sizeof(int), stream);
    fill_csr<<<eBlocks, TPB, 0, stream>>>(src_uc, dst_uc, rp_uc, deg, col_uc, E);

    // ---- CSR for relation iu (dst = user) ----
    hipMemsetAsync(deg, 0, (size_t)NU * sizeof(int), stream);
    deg_kernel<<<eBlocks, TPB, 0, stream>>>(dst_iu, deg, E);
    scan1<<<sBlocksU, 256, 0, stream>>>(deg, rp_iu, partials, NU);
    scan2<<<1, 1024, 0, stream>>>(partials, sBlocksU);
    scan3<<<sBlocksU, 256, 0, stream>>>(rp_iu, partials, NU, E);
    hipMemsetAsync(deg, 0, (size_t)NU * sizeof(int), stream);
    fill_csr<<<eBlocks, TPB, 0, stream>>>(src_iu, dst_iu, rp_iu, deg, col_iu, E);

    // ---- layer 1 ----
    gather_mean<<<gBlocksI, TPB, 0, stream>>>(x_user, rp_uc, col_uc, agg_i, NI);
    gemm_mfma<<<mBlocksI, TPB, 0, stream>>>(x_item, agg_i, WTH + 0 * WSTRIDE, WTL + 0 * WSTRIDE,
                                            b1_uc, out_item /*h1_item*/, NI, 1);
    gather_mean<<<gBlocksU, TPB, 0, stream>>>(x_item, rp_iu, col_iu, agg_u, NU);
    gemm_mfma<<<mBlocksU, TPB, 0, stream>>>(x_user, agg_u, WTH + 1 * WSTRIDE, WTL + 1 * WSTRIDE,
                                            b1_iu, out_user /*h1_user*/, NU, 1);

    // ---- layer 2: gathers first (consume h1 from d_out), then in-place GEMMs
    gather_mean<<<gBlocksI, TPB, 0, stream>>>(out_user /*h1_user*/, rp_uc, col_uc, agg_i, NI);
    gather_mean<<<gBlocksU, TPB, 0, stream>>>(out_item /*h1_item*/, rp_iu, col_iu, agg_u, NU);
    gemm_mfma<<<mBlocksI, TPB, 0, stream>>>(out_item, agg_i, WTH + 2 * WSTRIDE, WTL + 2 * WSTRIDE,
                                            b2_uc, out_item, NI, 0);
    gemm_mfma<<<mBlocksU, TPB, 0, stream>>>(out_user, agg_u, WTH + 3 * WSTRIDE, WTL + 3 * WSTRIDE,
                                            b2_iu, out_user, NU, 0);
}

// Round 5
// 696.460 us; speedup vs baseline: 6.1753x; 1.2437x over previous
//
#include <hip/hip_runtime.h>
#include <hip/hip_bf16.h>

#define D_ 128
#define H_ 128

typedef __attribute__((ext_vector_type(8))) short s8b;   // 8 bf16
typedef __attribute__((ext_vector_type(4))) float f4;    // MFMA acc

union U4 { uint u[4]; s8b v; uint4 q; };

// ---------------- degree ----------------
__global__ void deg_kernel(const int* __restrict__ dst, int* __restrict__ deg, int E) {
    int e = blockIdx.x * blockDim.x + threadIdx.x;
    if (e < E) atomicAdd(&deg[dst[e]], 1);
}

// ---------------- exclusive scan (3-kernel) ----------------
__global__ __launch_bounds__(256)
void scan1(const int* __restrict__ deg, int* __restrict__ rp,
           int* __restrict__ partials, int N) {
    int tid = threadIdx.x;
    int i = blockIdx.x * 256 + tid;
    int v = (i < N) ? deg[i] : 0;
    int lane = tid & 63, wid = tid >> 6;
    int x = v;
#pragma unroll
    for (int off = 1; off < 64; off <<= 1) {
        int y = __shfl_up(x, off, 64);
        if (lane >= off) x += y;
    }
    __shared__ int wsum[5];
    if (lane == 63) wsum[wid] = x;
    __syncthreads();
    if (tid == 0) {
        int a = wsum[0], b = wsum[1], c = wsum[2], d = wsum[3];
        wsum[0] = 0; wsum[1] = a; wsum[2] = a + b; wsum[3] = a + b + c;
        wsum[4] = a + b + c + d;
    }
    __syncthreads();
    if (i < N) rp[i] = wsum[wid] + x - v;
    if (tid == 0) partials[blockIdx.x] = wsum[4];
}

__global__ __launch_bounds__(1024)
void scan2(int* __restrict__ partials, int B) {
    __shared__ int buf[1024];
    int t = threadIdx.x;
    int v = (t < B) ? partials[t] : 0;
    buf[t] = v;
    __syncthreads();
    for (int off = 1; off < 1024; off <<= 1) {
        int add = (t >= off) ? buf[t - off] : 0;
        __syncthreads();
        buf[t] += add;
        __syncthreads();
    }
    if (t < B) partials[t] = buf[t] - v;
}

__global__ __launch_bounds__(256)
void scan3(int* __restrict__ rp, const int* __restrict__ partials, int N, int E) {
    int i = blockIdx.x * 256 + threadIdx.x;
    if (i < N) rp[i] += partials[blockIdx.x];
    if (i == 0) rp[N] = E;
}

// ---------------- CSR fill ----------------
__global__ void fill_csr(const int* __restrict__ src, const int* __restrict__ dst,
                         const int* __restrict__ rp, int* __restrict__ cursor,
                         int* __restrict__ col, int E) {
    int e = blockIdx.x * blockDim.x + threadIdx.x;
    if (e < E) {
        int d = dst[e];
        int slot = rp[d] + atomicAdd(&cursor[d], 1);
        col[slot] = src[e];
    }
}

// ---------------- gather-mean: 4 nodes per wave (16 lanes each), 2-edge unroll ----------------
__global__ __launch_bounds__(256)
void gather_mean(const float* __restrict__ x, const int* __restrict__ rp,
                 const int* __restrict__ col, float* __restrict__ out, int N) {
    long long gid = (long long)blockIdx.x * blockDim.x + threadIdx.x;
    int node = (int)(gid >> 4);
    int li = (int)(gid & 15);
    if (node >= N) return;
    int beg = rp[node], end = rp[node + 1];

    float4 a0 = make_float4(0.f, 0.f, 0.f, 0.f);
    float4 a1 = make_float4(0.f, 0.f, 0.f, 0.f);

    int e = beg;
    for (; e + 2 <= end; e += 2) {
        int s0 = col[e];
        int s1 = col[e + 1];
        const float4* p0 = (const float4*)(x + (size_t)s0 * 128 + li * 8);
        const float4* p1 = (const float4*)(x + (size_t)s1 * 128 + li * 8);
        float4 u0 = p0[0], u1 = p0[1];
        float4 v0 = p1[0], v1 = p1[1];
        a0.x += u0.x; a0.y += u0.y; a0.z += u0.z; a0.w += u0.w;
        a1.x += u1.x; a1.y += u1.y; a1.z += u1.z; a1.w += u1.w;
        a0.x += v0.x; a0.y += v0.y; a0.z += v0.z; a0.w += v0.w;
        a1.x += v1.x; a1.y += v1.y; a1.z += v1.z; a1.w += v1.w;
    }
    if (e < end) {
        int s0 = col[e];
        const float4* p0 = (const float4*)(x + (size_t)s0 * 128 + li * 8);
        float4 u0 = p0[0], u1 = p0[1];
        a0.x += u0.x; a0.y += u0.y; a0.z += u0.z; a0.w += u0.w;
        a1.x += u1.x; a1.y += u1.y; a1.z += u1.z; a1.w += u1.w;
    }

    int dg = end - beg;
    float inv = 1.0f / (float)(dg > 0 ? dg : 1);
    float4 o0 = make_float4(a0.x * inv, a0.y * inv, a0.z * inv, a0.w * inv);
    float4 o1 = make_float4(a1.x * inv, a1.y * inv, a1.z * inv, a1.w * inv);
    float4* q = (float4*)(out + (size_t)node * 128 + li * 8);
    q[0] = o0;
    q[1] = o1;
}

// ---------------- weight prep: transpose + bf16 h/l split ----------------
__global__ __launch_bounds__(256)
void prep_weights(const float* __restrict__ s0, const float* __restrict__ n0,
                  const float* __restrict__ s1, const float* __restrict__ n1,
                  const float* __restrict__ s2, const float* __restrict__ n2,
                  const float* __restrict__ s3, const float* __restrict__ n3,
                  ushort* __restrict__ WTH, ushort* __restrict__ WTL) {
    int g = blockIdx.y;
    int t = blockIdx.x * 256 + threadIdx.x;   // 0..4095
    int c = t & 127;
    int oct = t >> 7;                          // 0..31 (8 kv each)
    const float* self  = g == 0 ? s0 : g == 1 ? s1 : g == 2 ? s2 : s3;
    const float* neigh = g == 0 ? n0 : g == 1 ? n1 : g == 2 ? n2 : n3;
    uint hd[4], ld_[4];
#pragma unroll
    for (int p = 0; p < 4; ++p) {
        uint hpair = 0, lpair = 0;
#pragma unroll
        for (int q = 0; q < 2; ++q) {
            int kv = oct * 8 + p * 2 + q;
            const float* Wsrc = kv < 128 ? self : neigh;
            float f = Wsrc[(size_t)(kv & 127) * 128 + c];
            uint u = __float_as_uint(f);
            uint h = u >> 16;                            // truncate
            float r = f - __uint_as_float(u & 0xffff0000u);
            uint v = __float_as_uint(r);
            uint l = (v + 0x7fffu + ((v >> 16) & 1u)) >> 16;  // RNE
            hpair |= h << (16 * q);
            lpair |= l << (16 * q);
        }
        hd[p] = hpair; ld_[p] = lpair;
    }
    size_t base = ((size_t)g * 128 + c) * 256 + oct * 8;
    *(uint4*)(WTH + base) = make_uint4(hd[0], hd[1], hd[2], hd[3]);
    *(uint4*)(WTL + base) = make_uint4(ld_[0], ld_[1], ld_[2], ld_[3]);
}

// ---------------- MFMA GEMM: out[N,128] = A1@W_self + A2@W_neigh + bias ----------------
// Virtual K = 256 (ks 0..3 -> A1/self, 4..7 -> A2/neigh). Compensated bf16:
// acc = Ah@Wh + Al@Wh + Ah@Wl. 128x128 tile, 4 waves of 64x64, 16x16x32 MFMA.
__global__ __launch_bounds__(256)
void gemm_mfma(const float* __restrict__ A1, const float* __restrict__ A2,
               const ushort* __restrict__ WTh, const ushort* __restrict__ WTl,
               const float* __restrict__ bias, float* __restrict__ out,
               int N, int lrelu) {
    __shared__ s8b ldsAh[512];
    __shared__ s8b ldsAl[512];
    __shared__ s8b ldsWh[512];
    __shared__ s8b ldsWl[512];

    const int t = threadIdx.x;
    const int row0 = blockIdx.x * 128;
    const int lane = t & 63, w = t >> 6;
    const int mrow0 = (w & 1) * 64, ncol0 = (w >> 1) * 64;
    const int fr = lane & 15, hi = lane >> 4;

    // accumulators init with bias
    f4 acc[4][4];
    float bv[4];
#pragma unroll
    for (int n = 0; n < 4; ++n) bv[n] = bias[ncol0 + n * 16 + fr];
#pragma unroll
    for (int m = 0; m < 4; ++m)
#pragma unroll
        for (int n = 0; n < 4; ++n) acc[m][n] = (f4){bv[n], bv[n], bv[n], bv[n]};

    const int sr = t >> 1, half = t & 1;       // staging: row, k-half
    const int grow = row0 + sr;
    const int swz = (sr >> 1) & 3;             // same formula for A-row and W-col

    // precompute frag slot indices
    int aslot[4], wslot[4];
#pragma unroll
    for (int m = 0; m < 4; ++m) {
        int r = mrow0 + m * 16 + fr;
        aslot[m] = r * 4 + (hi ^ ((r >> 1) & 3));
    }
#pragma unroll
    for (int n = 0; n < 4; ++n) {
        int c = ncol0 + n * 16 + fr;
        wslot[n] = c * 4 + (hi ^ ((c >> 1) & 3));
    }

    for (int ks = 0; ks < 8; ++ks) {
        // ---- stage A: 128 rows x 32 k, fp32 -> bf16 h/l
        const float* __restrict__ As = (ks < 4) ? A1 : A2;
        const int k0 = (ks & 3) * 32 + half * 16;
        float e[16];
        if (grow < N) {
            const float4* p = (const float4*)(As + (size_t)grow * 128 + k0);
            float4 q0 = p[0], q1 = p[1], q2 = p[2], q3 = p[3];
            e[0] = q0.x; e[1] = q0.y; e[2] = q0.z; e[3] = q0.w;
            e[4] = q1.x; e[5] = q1.y; e[6] = q1.z; e[7] = q1.w;
            e[8] = q2.x; e[9] = q2.y; e[10] = q2.z; e[11] = q2.w;
            e[12] = q3.x; e[13] = q3.y; e[14] = q3.z; e[15] = q3.w;
        } else {
#pragma unroll
            for (int i = 0; i < 16; ++i) e[i] = 0.f;
        }
        uint hd[8], ld_[8];
#pragma unroll
        for (int p = 0; p < 8; ++p) {
            uint u0 = __float_as_uint(e[2 * p]);
            uint u1 = __float_as_uint(e[2 * p + 1]);
            hd[p] = (u0 >> 16) | (u1 & 0xffff0000u);
            float r0 = e[2 * p] - __uint_as_float(u0 & 0xffff0000u);
            float r1 = e[2 * p + 1] - __uint_as_float(u1 & 0xffff0000u);
            uint v0 = __float_as_uint(r0), v1 = __float_as_uint(r1);
            uint l0 = (v0 + 0x7fffu + ((v0 >> 16) & 1u)) >> 16;
            uint l1 = (v1 + 0x7fffu + ((v1 >> 16) & 1u)) >> 16;
            ld_[p] = l0 | (l1 << 16);
        }
        {
            U4 a0; a0.u[0] = hd[0]; a0.u[1] = hd[1]; a0.u[2] = hd[2]; a0.u[3] = hd[3];
            U4 a1; a1.u[0] = hd[4]; a1.u[1] = hd[5]; a1.u[2] = hd[6]; a1.u[3] = hd[7];
            U4 b0; b0.u[0] = ld_[0]; b0.u[1] = ld_[1]; b0.u[2] = ld_[2]; b0.u[3] = ld_[3];
            U4 b1; b1.u[0] = ld_[4]; b1.u[1] = ld_[5]; b1.u[2] = ld_[6]; b1.u[3] = ld_[7];
            int h0 = half * 2, h1 = half * 2 + 1;
            ldsAh[sr * 4 + (h0 ^ swz)] = a0.v;
            ldsAh[sr * 4 + (h1 ^ swz)] = a1.v;
            ldsAl[sr * 4 + (h0 ^ swz)] = b0.v;
            ldsAl[sr * 4 + (h1 ^ swz)] = b1.v;
        }
        // ---- stage W: pre-split/transposed global -> LDS (swizzled)
        {
            size_t wbase = (size_t)sr * 256 + ks * 32 + half * 16;
            U4 wh0, wh1, wl0, wl1;
            wh0.q = *(const uint4*)(WTh + wbase);
            wh1.q = *(const uint4*)(WTh + wbase + 8);
            wl0.q = *(const uint4*)(WTl + wbase);
            wl1.q = *(const uint4*)(WTl + wbase + 8);
            int h0 = half * 2, h1 = half * 2 + 1;
            ldsWh[sr * 4 + (h0 ^ swz)] = wh0.v;
            ldsWh[sr * 4 + (h1 ^ swz)] = wh1.v;
            ldsWl[sr * 4 + (h0 ^ swz)] = wl0.v;
            ldsWl[sr * 4 + (h1 ^ swz)] = wl1.v;
        }
        __syncthreads();

        // ---- compute: 48 MFMAs per wave
        s8b ah[4], al[4];
#pragma unroll
        for (int m = 0; m < 4; ++m) { ah[m] = ldsAh[aslot[m]]; al[m] = ldsAl[aslot[m]]; }
#pragma unroll
        for (int n = 0; n < 4; ++n) {
            s8b wh = ldsWh[wslot[n]];
            s8b wl = ldsWl[wslot[n]];
#pragma unroll
            for (int m = 0; m < 4; ++m) {
                acc[m][n] = __builtin_amdgcn_mfma_f32_16x16x32_bf16(ah[m], wh, acc[m][n], 0, 0, 0);
                acc[m][n] = __builtin_amdgcn_mfma_f32_16x16x32_bf16(al[m], wh, acc[m][n], 0, 0, 0);
                acc[m][n] = __builtin_amdgcn_mfma_f32_16x16x32_bf16(ah[m], wl, acc[m][n], 0, 0, 0);
            }
        }
        __syncthreads();
    }

    // ---- epilogue
#pragma unroll
    for (int m = 0; m < 4; ++m) {
#pragma unroll
        for (int r = 0; r < 4; ++r) {
            int row = row0 + mrow0 + m * 16 + hi * 4 + r;
            if (row >= N) continue;
#pragma unroll
            for (int n = 0; n < 4; ++n) {
                float v = acc[m][n][r];
                if (lrelu) v = v > 0.f ? v : 0.01f * v;
                out[(size_t)row * 128 + ncol0 + n * 16 + fr] = v;
            }
        }
    }
}

extern "C" void kernel_launch(void* const* d_in, const int* in_sizes, int n_in,
                              void* d_out, int out_size, void* d_ws, size_t ws_size,
                              hipStream_t stream) {
    const float* x_user     = (const float*)d_in[0];
    const float* x_item     = (const float*)d_in[1];
    const float* w1_self_uc = (const float*)d_in[2];
    const float* w1_neigh_uc= (const float*)d_in[3];
    const float* b1_uc      = (const float*)d_in[4];
    const float* w1_self_iu = (const float*)d_in[5];
    const float* w1_neigh_iu= (const float*)d_in[6];
    const float* b1_iu      = (const float*)d_in[7];
    const float* w2_self_uc = (const float*)d_in[8];
    const float* w2_neigh_uc= (const float*)d_in[9];
    const float* b2_uc      = (const float*)d_in[10];
    const float* w2_self_iu = (const float*)d_in[11];
    const float* w2_neigh_iu= (const float*)d_in[12];
    const float* b2_iu      = (const float*)d_in[13];
    const int* src_uc = (const int*)d_in[14];
    const int* dst_uc = (const int*)d_in[15];
    const int* src_iu = (const int*)d_in[16];
    const int* dst_iu = (const int*)d_in[17];

    const int NU = in_sizes[0] / D_;
    const int NI = in_sizes[1] / D_;
    const int E  = in_sizes[14];

    float* out_user = (float*)d_out;                   // doubles as h1_user scratch
    float* out_item = (float*)d_out + (size_t)NU * H_; // doubles as h1_item scratch

    // workspace layout (16B-aligned chunks first)
    char* ws = (char*)d_ws;
    const size_t FEAT_BYTES = (size_t)200000 * 128 * sizeof(float); // 102.4 MB
    float* agg_i  = (float*)ws;  ws += FEAT_BYTES;
    float* agg_u  = (float*)ws;  ws += FEAT_BYTES;
    ushort* WTH   = (ushort*)ws; ws += (size_t)4 * 128 * 256 * sizeof(ushort); // 256KB
    ushort* WTL   = (ushort*)ws; ws += (size_t)4 * 128 * 256 * sizeof(ushort);
    int* rp_uc    = (int*)ws;    ws += (size_t)(NI + 1) * sizeof(int);
    int* rp_iu    = (int*)ws;    ws += (size_t)(NU + 1) * sizeof(int);
    int* col_uc   = (int*)ws;    ws += (size_t)E * sizeof(int);
    int* col_iu   = (int*)ws;    ws += (size_t)E * sizeof(int);
    int* deg      = (int*)ws;    ws += (size_t)200000 * sizeof(int);
    int* partials = (int*)ws;    ws += (size_t)1024 * sizeof(int);

    const int TPB = 256;
    const int eBlocks  = (E + TPB - 1) / TPB;
    const int sBlocksI = (NI + 255) / 256;
    const int sBlocksU = (NU + 255) / 256;
    const int gBlocksI = (int)(((long long)NI * 16 + TPB - 1) / TPB);
    const int gBlocksU = (int)(((long long)NU * 16 + TPB - 1) / TPB);
    const int mBlocksI = (NI + 127) / 128;
    const int mBlocksU = (NU + 127) / 128;

    // per-config weight bases: g0=l1_uc, g1=l1_iu, g2=l2_uc, g3=l2_iu
    const size_t WSTRIDE = (size_t)128 * 256;

    // ---- weight prep (independent of CSR) ----
    prep_weights<<<dim3(16, 4), 256, 0, stream>>>(
        w1_self_uc, w1_neigh_uc, w1_self_iu, w1_neigh_iu,
        w2_self_uc, w2_neigh_uc, w2_self_iu, w2_neigh_iu, WTH, WTL);

    // ---- CSR for relation uc (dst = item) ----
    hipMemsetAsync(deg, 0, (size_t)NI * sizeof(int), stream);
    deg_kernel<<<eBlocks, TPB, 0, stream>>>(dst_uc, deg, E);
    scan1<<<sBlocksI, 256, 0, stream>>>(deg, rp_uc, partials, NI);
    scan2<<<1, 1024, 0, stream>>>(partials, sBlocksI);
    scan3<<<sBlocksI, 256, 0, stream>>>(rp_uc, partials, NI, E);
    hipMemsetAsync(deg, 0, (size_t)NI * sizeof(int), stream);
    fill_csr<<<eBlocks, TPB, 0, stream>>>(src_uc, dst_uc, rp_uc, deg, col_uc, E);

    // ---- CSR for relation iu (dst = user) ----
    hipMemsetAsync(deg, 0, (size_t)NU * sizeof(int), stream);
    deg_kernel<<<eBlocks, TPB, 0, stream>>>(dst_iu, deg, E);
    scan1<<<sBlocksU, 256, 0, stream>>>(deg, rp_iu, partials, NU);
    scan2<<<1, 1024, 0, stream>>>(partials, sBlocksU);
    scan3<<<sBlocksU, 256, 0, stream>>>(rp_iu, partials, NU, E);
    hipMemsetAsync(deg, 0, (size_t)NU * sizeof(int), stream);
    fill_csr<<<eBlocks, TPB, 0, stream>>>(src_iu, dst_iu, rp_iu, deg, col_iu, E);

    // ---- layer 1 ----
    gather_mean<<<gBlocksI, TPB, 0, stream>>>(x_user, rp_uc, col_uc, agg_i, NI);
    gemm_mfma<<<mBlocksI, TPB, 0, stream>>>(x_item, agg_i, WTH + 0 * WSTRIDE, WTL + 0 * WSTRIDE,
                                            b1_uc, out_item /*h1_item*/, NI, 1);
    gather_mean<<<gBlocksU, TPB, 0, stream>>>(x_item, rp_iu, col_iu, agg_u, NU);
    gemm_mfma<<<mBlocksU, TPB, 0, stream>>>(x_user, agg_u, WTH + 1 * WSTRIDE, WTL + 1 * WSTRIDE,
                                            b1_iu, out_user /*h1_user*/, NU, 1);

    // ---- layer 2: gathers first (consume h1 from d_out), then in-place GEMMs
    gather_mean<<<gBlocksI, TPB, 0, stream>>>(out_user /*h1_user*/, rp_uc, col_uc, agg_i, NI);
    gather_mean<<<gBlocksU, TPB, 0, stream>>>(out_item /*h1_item*/, rp_iu, col_iu, agg_u, NU);
    gemm_mfma<<<mBlocksI, TPB, 0, stream>>>(out_item, agg_i, WTH + 2 * WSTRIDE, WTL + 2 * WSTRIDE,
                                            b2_uc, out_item, NI, 0);
    gemm_mfma<<<mBlocksU, TPB, 0, stream>>>(out_user, agg_u, WTH + 3 * WSTRIDE, WTL + 3 * WSTRIDE,
                                            b2_iu, out_user, NU, 0);
}

// Round 6
// 645.173 us; speedup vs baseline: 6.6662x; 1.0795x over previous
//
#include <hip/hip_runtime.h>
#include <hip/hip_bf16.h>

#define D_ 128
#define H_ 128

typedef __attribute__((ext_vector_type(8))) short s8b;   // 8 bf16
typedef __attribute__((ext_vector_type(4))) float f4;    // MFMA acc

union U4 { uint u[4]; s8b v; uint4 q; };

// ---------------- degree (both relations) ----------------
__global__ void deg2_kernel(const int* __restrict__ dstA, const int* __restrict__ dstB,
                            int* __restrict__ degA, int* __restrict__ degB, int E) {
    int e = blockIdx.x * blockDim.x + threadIdx.x;
    const int* dst = blockIdx.y ? dstB : dstA;
    int* deg = blockIdx.y ? degB : degA;
    if (e < E) atomicAdd(&deg[dst[e]], 1);
}

// ---------------- exclusive scan (3-kernel, both relations) ----------------
__global__ __launch_bounds__(256)
void scan1m(const int* __restrict__ degA, const int* __restrict__ degB,
            int* __restrict__ rpA, int* __restrict__ rpB,
            int* __restrict__ partA, int* __restrict__ partB, int N) {
    const int* deg = blockIdx.y ? degB : degA;
    int* rp = blockIdx.y ? rpB : rpA;
    int* partials = blockIdx.y ? partB : partA;
    int tid = threadIdx.x;
    int i = blockIdx.x * 256 + tid;
    int v = (i < N) ? deg[i] : 0;
    int lane = tid & 63, wid = tid >> 6;
    int x = v;
#pragma unroll
    for (int off = 1; off < 64; off <<= 1) {
        int y = __shfl_up(x, off, 64);
        if (lane >= off) x += y;
    }
    __shared__ int wsum[5];
    if (lane == 63) wsum[wid] = x;
    __syncthreads();
    if (tid == 0) {
        int a = wsum[0], b = wsum[1], c = wsum[2], d = wsum[3];
        wsum[0] = 0; wsum[1] = a; wsum[2] = a + b; wsum[3] = a + b + c;
        wsum[4] = a + b + c + d;
    }
    __syncthreads();
    if (i < N) rp[i] = wsum[wid] + x - v;
    if (tid == 0) partials[blockIdx.x] = wsum[4];
}

__global__ __launch_bounds__(1024)
void scan2m(int* __restrict__ partA, int* __restrict__ partB, int B) {
    int* partials = blockIdx.x ? partB : partA;
    __shared__ int buf[1024];
    int t = threadIdx.x;
    int v = (t < B) ? partials[t] : 0;
    buf[t] = v;
    __syncthreads();
    for (int off = 1; off < 1024; off <<= 1) {
        int add = (t >= off) ? buf[t - off] : 0;
        __syncthreads();
        buf[t] += add;
        __syncthreads();
    }
    if (t < B) partials[t] = buf[t] - v;
}

__global__ __launch_bounds__(256)
void scan3m(int* __restrict__ rpA, int* __restrict__ rpB,
            const int* __restrict__ partA, const int* __restrict__ partB, int N, int E) {
    int* rp = blockIdx.y ? rpB : rpA;
    const int* partials = blockIdx.y ? partB : partA;
    int i = blockIdx.x * 256 + threadIdx.x;
    if (i < N) rp[i] += partials[blockIdx.x];
    if (i == 0) rp[N] = E;
}

// ---------------- CSR fill (both relations) + first-4 pack ----------------
__global__ void fill2_csr(const int* __restrict__ srcA, const int* __restrict__ dstA,
                          const int* __restrict__ rpA, int* __restrict__ curA,
                          int* __restrict__ colA, int* __restrict__ colpA,
                          const int* __restrict__ srcB, const int* __restrict__ dstB,
                          const int* __restrict__ rpB, int* __restrict__ curB,
                          int* __restrict__ colB, int* __restrict__ colpB, int E) {
    int e = blockIdx.x * blockDim.x + threadIdx.x;
    if (e >= E) return;
    const int* src = blockIdx.y ? srcB : srcA;
    const int* dst = blockIdx.y ? dstB : dstA;
    const int* rp  = blockIdx.y ? rpB : rpA;
    int* cursor = blockIdx.y ? curB : curA;
    int* col    = blockIdx.y ? colB : colA;
    int* colp   = blockIdx.y ? colpB : colpA;
    int d = dst[e];
    int s = src[e];
    int idx = atomicAdd(&cursor[d], 1);
    col[rp[d] + idx] = s;
    if (idx < 4) colp[d * 4 + idx] = s;
}

// ---------------- gather-mean: 4 nodes/wave (16 lanes each), first-4 via colp ----------------
__device__ __forceinline__ void fma4(float4& a, const float4& u, float w) {
    a.x = fmaf(u.x, w, a.x); a.y = fmaf(u.y, w, a.y);
    a.z = fmaf(u.z, w, a.z); a.w = fmaf(u.w, w, a.w);
}

__device__ __forceinline__ void gather_node(const float* __restrict__ x,
                                            const int* __restrict__ rp,
                                            const int* __restrict__ col,
                                            const int* __restrict__ colp,
                                            float* __restrict__ out,
                                            int node, int li) {
    int beg = rp[node];
    int end = rp[node + 1];
    int dg = end - beg;
    int4 c4 = *(const int4*)(colp + (size_t)node * 4);   // parallel with rp loads
    int s0 = dg > 0 ? c4.x : 0;
    int s1 = dg > 1 ? c4.y : 0;
    int s2 = dg > 2 ? c4.z : 0;
    int s3 = dg > 3 ? c4.w : 0;
    const float4* p0 = (const float4*)(x + (size_t)s0 * 128 + li * 8);
    const float4* p1 = (const float4*)(x + (size_t)s1 * 128 + li * 8);
    const float4* p2 = (const float4*)(x + (size_t)s2 * 128 + li * 8);
    const float4* p3 = (const float4*)(x + (size_t)s3 * 128 + li * 8);
    float4 u00 = p0[0], u01 = p0[1];
    float4 u10 = p1[0], u11 = p1[1];
    float4 u20 = p2[0], u21 = p2[1];
    float4 u30 = p3[0], u31 = p3[1];
    float w0 = dg > 0 ? 1.f : 0.f;
    float w1 = dg > 1 ? 1.f : 0.f;
    float w2 = dg > 2 ? 1.f : 0.f;
    float w3 = dg > 3 ? 1.f : 0.f;
    float4 a0 = make_float4(0.f, 0.f, 0.f, 0.f);
    float4 a1 = make_float4(0.f, 0.f, 0.f, 0.f);
    fma4(a0, u00, w0); fma4(a1, u01, w0);
    fma4(a0, u10, w1); fma4(a1, u11, w1);
    fma4(a0, u20, w2); fma4(a1, u21, w2);
    fma4(a0, u30, w3); fma4(a1, u31, w3);
    for (int e = beg + 4; e < end; ++e) {           // rare (deg>4, ~9%)
        int s = col[e];
        const float4* p = (const float4*)(x + (size_t)s * 128 + li * 8);
        float4 v0 = p[0], v1 = p[1];
        a0.x += v0.x; a0.y += v0.y; a0.z += v0.z; a0.w += v0.w;
        a1.x += v1.x; a1.y += v1.y; a1.z += v1.z; a1.w += v1.w;
    }
    float inv = 1.0f / (float)(dg > 0 ? dg : 1);
    float4 o0 = make_float4(a0.x * inv, a0.y * inv, a0.z * inv, a0.w * inv);
    float4 o1 = make_float4(a1.x * inv, a1.y * inv, a1.z * inv, a1.w * inv);
    float4* q = (float4*)(out + (size_t)node * 128 + li * 8);
    q[0] = o0;
    q[1] = o1;
}

__global__ __launch_bounds__(256)
void gather2(const float* __restrict__ xA, const int* __restrict__ rpA,
             const int* __restrict__ colA, const int* __restrict__ colpA,
             float* __restrict__ outA, int NA,
             const float* __restrict__ xB, const int* __restrict__ rpB,
             const int* __restrict__ colB, const int* __restrict__ colpB,
             float* __restrict__ outB, int NB, int blocksA) {
    bool isA = (int)blockIdx.x < blocksA;
    int bid = isA ? blockIdx.x : blockIdx.x - blocksA;
    long long gid = (long long)bid * 256 + threadIdx.x;
    int node = (int)(gid >> 4);
    int li = (int)(gid & 15);
    if (isA) {
        if (node < NA) gather_node(xA, rpA, colA, colpA, outA, node, li);
    } else {
        if (node < NB) gather_node(xB, rpB, colB, colpB, outB, node, li);
    }
}

// ---------------- weight prep: transpose + bf16 h/l split ----------------
__global__ __launch_bounds__(256)
void prep_weights(const float* __restrict__ s0, const float* __restrict__ n0,
                  const float* __restrict__ s1, const float* __restrict__ n1,
                  const float* __restrict__ s2, const float* __restrict__ n2,
                  const float* __restrict__ s3, const float* __restrict__ n3,
                  ushort* __restrict__ WTH, ushort* __restrict__ WTL) {
    int g = blockIdx.y;
    int t = blockIdx.x * 256 + threadIdx.x;   // 0..4095
    int c = t & 127;
    int oct = t >> 7;                          // 0..31 (8 kv each)
    const float* self  = g == 0 ? s0 : g == 1 ? s1 : g == 2 ? s2 : s3;
    const float* neigh = g == 0 ? n0 : g == 1 ? n1 : g == 2 ? n2 : n3;
    uint hd[4], ld_[4];
#pragma unroll
    for (int p = 0; p < 4; ++p) {
        uint hpair = 0, lpair = 0;
#pragma unroll
        for (int q = 0; q < 2; ++q) {
            int kv = oct * 8 + p * 2 + q;
            const float* Wsrc = kv < 128 ? self : neigh;
            float f = Wsrc[(size_t)(kv & 127) * 128 + c];
            uint u = __float_as_uint(f);
            uint h = u >> 16;                            // truncate
            float r = f - __uint_as_float(u & 0xffff0000u);
            uint v = __float_as_uint(r);
            uint l = (v + 0x7fffu + ((v >> 16) & 1u)) >> 16;  // RNE
            hpair |= h << (16 * q);
            lpair |= l << (16 * q);
        }
        hd[p] = hpair; ld_[p] = lpair;
    }
    size_t base = ((size_t)g * 128 + c) * 256 + oct * 8;
    *(uint4*)(WTH + base) = make_uint4(hd[0], hd[1], hd[2], hd[3]);
    *(uint4*)(WTL + base) = make_uint4(ld_[0], ld_[1], ld_[2], ld_[3]);
}

// ---------------- MFMA GEMM body ----------------
// out[N,128] = A1@W_self + A2@W_neigh + bias ; compensated bf16 (Ah@Wh+Al@Wh+Ah@Wl)
// 128x128 tile, 4 waves of 64x64, 16x16x32 MFMA. In-place (out==A1) safe per-block.
__device__ __forceinline__ void gemm_body(const float* __restrict__ A1,
                                          const float* __restrict__ A2,
                                          const ushort* __restrict__ WTh,
                                          const ushort* __restrict__ WTl,
                                          const float* __restrict__ bias,
                                          float* __restrict__ out,
                                          int N, int lrelu, int bid,
                                          s8b* ldsAh, s8b* ldsAl, s8b* ldsWh, s8b* ldsWl) {
    const int t = threadIdx.x;
    const int row0 = bid * 128;
    const int lane = t & 63, w = t >> 6;
    const int mrow0 = (w & 1) * 64, ncol0 = (w >> 1) * 64;
    const int fr = lane & 15, hi = lane >> 4;

    f4 acc[4][4];
    float bv[4];
#pragma unroll
    for (int n = 0; n < 4; ++n) bv[n] = bias[ncol0 + n * 16 + fr];
#pragma unroll
    for (int m = 0; m < 4; ++m)
#pragma unroll
        for (int n = 0; n < 4; ++n) acc[m][n] = (f4){bv[n], bv[n], bv[n], bv[n]};

    const int sr = t >> 1, half = t & 1;
    const int grow = row0 + sr;
    const int swz = (sr >> 1) & 3;

    int aslot[4], wslot[4];
#pragma unroll
    for (int m = 0; m < 4; ++m) {
        int r = mrow0 + m * 16 + fr;
        aslot[m] = r * 4 + (hi ^ ((r >> 1) & 3));
    }
#pragma unroll
    for (int n = 0; n < 4; ++n) {
        int c = ncol0 + n * 16 + fr;
        wslot[n] = c * 4 + (hi ^ ((c >> 1) & 3));
    }

    for (int ks = 0; ks < 8; ++ks) {
        const float* __restrict__ As = (ks < 4) ? A1 : A2;
        const int k0 = (ks & 3) * 32 + half * 16;
        float e[16];
        if (grow < N) {
            const float4* p = (const float4*)(As + (size_t)grow * 128 + k0);
            float4 q0 = p[0], q1 = p[1], q2 = p[2], q3 = p[3];
            e[0] = q0.x; e[1] = q0.y; e[2] = q0.z; e[3] = q0.w;
            e[4] = q1.x; e[5] = q1.y; e[6] = q1.z; e[7] = q1.w;
            e[8] = q2.x; e[9] = q2.y; e[10] = q2.z; e[11] = q2.w;
            e[12] = q3.x; e[13] = q3.y; e[14] = q3.z; e[15] = q3.w;
        } else {
#pragma unroll
            for (int i = 0; i < 16; ++i) e[i] = 0.f;
        }
        uint hd[8], ld_[8];
#pragma unroll
        for (int p = 0; p < 8; ++p) {
            uint u0 = __float_as_uint(e[2 * p]);
            uint u1 = __float_as_uint(e[2 * p + 1]);
            hd[p] = (u0 >> 16) | (u1 & 0xffff0000u);
            float r0 = e[2 * p] - __uint_as_float(u0 & 0xffff0000u);
            float r1 = e[2 * p + 1] - __uint_as_float(u1 & 0xffff0000u);
            uint v0 = __float_as_uint(r0), v1 = __float_as_uint(r1);
            uint l0 = (v0 + 0x7fffu + ((v0 >> 16) & 1u)) >> 16;
            uint l1 = (v1 + 0x7fffu + ((v1 >> 16) & 1u)) >> 16;
            ld_[p] = l0 | (l1 << 16);
        }
        {
            U4 a0; a0.u[0] = hd[0]; a0.u[1] = hd[1]; a0.u[2] = hd[2]; a0.u[3] = hd[3];
            U4 a1; a1.u[0] = hd[4]; a1.u[1] = hd[5]; a1.u[2] = hd[6]; a1.u[3] = hd[7];
            U4 b0; b0.u[0] = ld_[0]; b0.u[1] = ld_[1]; b0.u[2] = ld_[2]; b0.u[3] = ld_[3];
            U4 b1; b1.u[0] = ld_[4]; b1.u[1] = ld_[5]; b1.u[2] = ld_[6]; b1.u[3] = ld_[7];
            int h0 = half * 2, h1 = half * 2 + 1;
            ldsAh[sr * 4 + (h0 ^ swz)] = a0.v;
            ldsAh[sr * 4 + (h1 ^ swz)] = a1.v;
            ldsAl[sr * 4 + (h0 ^ swz)] = b0.v;
            ldsAl[sr * 4 + (h1 ^ swz)] = b1.v;
        }
        {
            size_t wbase = (size_t)sr * 256 + ks * 32 + half * 16;
            U4 wh0, wh1, wl0, wl1;
            wh0.q = *(const uint4*)(WTh + wbase);
            wh1.q = *(const uint4*)(WTh + wbase + 8);
            wl0.q = *(const uint4*)(WTl + wbase);
            wl1.q = *(const uint4*)(WTl + wbase + 8);
            int h0 = half * 2, h1 = half * 2 + 1;
            ldsWh[sr * 4 + (h0 ^ swz)] = wh0.v;
            ldsWh[sr * 4 + (h1 ^ swz)] = wh1.v;
            ldsWl[sr * 4 + (h0 ^ swz)] = wl0.v;
            ldsWl[sr * 4 + (h1 ^ swz)] = wl1.v;
        }
        __syncthreads();

        s8b ah[4], al[4];
#pragma unroll
        for (int m = 0; m < 4; ++m) { ah[m] = ldsAh[aslot[m]]; al[m] = ldsAl[aslot[m]]; }
#pragma unroll
        for (int n = 0; n < 4; ++n) {
            s8b wh = ldsWh[wslot[n]];
            s8b wl = ldsWl[wslot[n]];
#pragma unroll
            for (int m = 0; m < 4; ++m) {
                acc[m][n] = __builtin_amdgcn_mfma_f32_16x16x32_bf16(ah[m], wh, acc[m][n], 0, 0, 0);
                acc[m][n] = __builtin_amdgcn_mfma_f32_16x16x32_bf16(al[m], wh, acc[m][n], 0, 0, 0);
                acc[m][n] = __builtin_amdgcn_mfma_f32_16x16x32_bf16(ah[m], wl, acc[m][n], 0, 0, 0);
            }
        }
        __syncthreads();
    }

#pragma unroll
    for (int m = 0; m < 4; ++m) {
#pragma unroll
        for (int r = 0; r < 4; ++r) {
            int row = row0 + mrow0 + m * 16 + hi * 4 + r;
            if (row >= N) continue;
#pragma unroll
            for (int n = 0; n < 4; ++n) {
                float v = acc[m][n][r];
                if (lrelu) v = v > 0.f ? v : 0.01f * v;
                out[(size_t)row * 128 + ncol0 + n * 16 + fr] = v;
            }
        }
    }
}

__global__ __launch_bounds__(256)
void gemm2(const float* __restrict__ A1a, const float* __restrict__ A2a,
           const ushort* __restrict__ WTha, const ushort* __restrict__ WTla,
           const float* __restrict__ ba, float* __restrict__ outa, int Na,
           const float* __restrict__ A1b, const float* __restrict__ A2b,
           const ushort* __restrict__ WThb, const ushort* __restrict__ WTlb,
           const float* __restrict__ bb, float* __restrict__ outb, int Nb,
           int blocksA, int lrelu) {
    __shared__ s8b ldsAh[512];
    __shared__ s8b ldsAl[512];
    __shared__ s8b ldsWh[512];
    __shared__ s8b ldsWl[512];
    bool isA = (int)blockIdx.x < blocksA;
    int bid = isA ? blockIdx.x : blockIdx.x - blocksA;
    if (isA)
        gemm_body(A1a, A2a, WTha, WTla, ba, outa, Na, lrelu, bid, ldsAh, ldsAl, ldsWh, ldsWl);
    else
        gemm_body(A1b, A2b, WThb, WTlb, bb, outb, Nb, lrelu, bid, ldsAh, ldsAl, ldsWh, ldsWl);
}

extern "C" void kernel_launch(void* const* d_in, const int* in_sizes, int n_in,
                              void* d_out, int out_size, void* d_ws, size_t ws_size,
                              hipStream_t stream) {
    const float* x_user     = (const float*)d_in[0];
    const float* x_item     = (const float*)d_in[1];
    const float* w1_self_uc = (const float*)d_in[2];
    const float* w1_neigh_uc= (const float*)d_in[3];
    const float* b1_uc      = (const float*)d_in[4];
    const float* w1_self_iu = (const float*)d_in[5];
    const float* w1_neigh_iu= (const float*)d_in[6];
    const float* b1_iu      = (const float*)d_in[7];
    const float* w2_self_uc = (const float*)d_in[8];
    const float* w2_neigh_uc= (const float*)d_in[9];
    const float* b2_uc      = (const float*)d_in[10];
    const float* w2_self_iu = (const float*)d_in[11];
    const float* w2_neigh_iu= (const float*)d_in[12];
    const float* b2_iu      = (const float*)d_in[13];
    const int* src_uc = (const int*)d_in[14];
    const int* dst_uc = (const int*)d_in[15];
    const int* src_iu = (const int*)d_in[16];
    const int* dst_iu = (const int*)d_in[17];

    const int NU = in_sizes[0] / D_;
    const int NI = in_sizes[1] / D_;
    const int E  = in_sizes[14];

    float* out_user = (float*)d_out;                   // doubles as h1_user scratch
    float* out_item = (float*)d_out + (size_t)NU * H_; // doubles as h1_item scratch

    // workspace layout (16B-aligned chunks first)
    char* ws = (char*)d_ws;
    const size_t FEAT_BYTES = (size_t)200000 * 128 * sizeof(float); // 102.4 MB
    float* agg_i   = (float*)ws;  ws += FEAT_BYTES;
    float* agg_u   = (float*)ws;  ws += FEAT_BYTES;
    ushort* WTH    = (ushort*)ws; ws += (size_t)4 * 128 * 256 * sizeof(ushort); // 256KB
    ushort* WTL    = (ushort*)ws; ws += (size_t)4 * 128 * 256 * sizeof(ushort);
    int* colp_uc   = (int*)ws;    ws += (size_t)200000 * 4 * sizeof(int);  // 3.2MB
    int* colp_iu   = (int*)ws;    ws += (size_t)200000 * 4 * sizeof(int);
    int* rp_uc     = (int*)ws;    ws += (size_t)(NI + 1) * sizeof(int);
    int* rp_iu     = (int*)ws;    ws += (size_t)(NU + 1) * sizeof(int);
    int* col_uc    = (int*)ws;    ws += (size_t)E * sizeof(int);
    int* col_iu    = (int*)ws;    ws += (size_t)E * sizeof(int);
    int* deg_uc    = (int*)ws;    ws += (size_t)200000 * sizeof(int);
    int* deg_iu    = (int*)ws;    ws += (size_t)200000 * sizeof(int);
    int* cur_uc    = (int*)ws;    ws += (size_t)200000 * sizeof(int);
    int* cur_iu    = (int*)ws;    ws += (size_t)200000 * sizeof(int);
    int* partA     = (int*)ws;    ws += (size_t)1024 * sizeof(int);
    int* partB     = (int*)ws;    ws += (size_t)1024 * sizeof(int);

    const int TPB = 256;
    const int eBlocks  = (E + TPB - 1) / TPB;
    const int sBlocks  = (200000 + 255) / 256;                 // NI == NU == 200000
    const int gBlocksI = (int)(((long long)NI * 16 + TPB - 1) / TPB);
    const int gBlocksU = (int)(((long long)NU * 16 + TPB - 1) / TPB);
    const int mBlocksI = (NI + 127) / 128;
    const int mBlocksU = (NU + 127) / 128;
    const size_t WSTRIDE = (size_t)128 * 256;  // g0=l1_uc g1=l1_iu g2=l2_uc g3=l2_iu

    // ---- init counters (deg + cursor, both relations: contiguous region) ----
    hipMemsetAsync(deg_uc, 0, (size_t)4 * 200000 * sizeof(int), stream); // deg_uc..cur_iu

    // ---- weight prep ----
    prep_weights<<<dim3(16, 4), 256, 0, stream>>>(
        w1_self_uc, w1_neigh_uc, w1_self_iu, w1_neigh_iu,
        w2_self_uc, w2_neigh_uc, w2_self_iu, w2_neigh_iu, WTH, WTL);

    // ---- CSR build (both relations in each dispatch) ----
    deg2_kernel<<<dim3(eBlocks, 2), TPB, 0, stream>>>(dst_uc, dst_iu, deg_uc, deg_iu, E);
    scan1m<<<dim3(sBlocks, 2), 256, 0, stream>>>(deg_uc, deg_iu, rp_uc, rp_iu, partA, partB, 200000);
    scan2m<<<2, 1024, 0, stream>>>(partA, partB, sBlocks);
    scan3m<<<dim3(sBlocks, 2), 256, 0, stream>>>(rp_uc, rp_iu, partA, partB, 200000, E);
    fill2_csr<<<dim3(eBlocks, 2), TPB, 0, stream>>>(src_uc, dst_uc, rp_uc, cur_uc, col_uc, colp_uc,
                                                    src_iu, dst_iu, rp_iu, cur_iu, col_iu, colp_iu, E);

    // ---- layer 1: both gathers in one launch, both GEMMs in one launch ----
    gather2<<<gBlocksI + gBlocksU, TPB, 0, stream>>>(
        x_user, rp_uc, col_uc, colp_uc, agg_i, NI,
        x_item, rp_iu, col_iu, colp_iu, agg_u, NU, gBlocksI);
    gemm2<<<mBlocksI + mBlocksU, TPB, 0, stream>>>(
        x_item, agg_i, WTH + 0 * WSTRIDE, WTL + 0 * WSTRIDE, b1_uc, out_item, NI,
        x_user, agg_u, WTH + 1 * WSTRIDE, WTL + 1 * WSTRIDE, b1_iu, out_user, NU,
        mBlocksI, 1);

    // ---- layer 2 ----
    gather2<<<gBlocksI + gBlocksU, TPB, 0, stream>>>(
        out_user, rp_uc, col_uc, colp_uc, agg_i, NI,
        out_item, rp_iu, col_iu, colp_iu, agg_u, NU, gBlocksI);
    gemm2<<<mBlocksI + mBlocksU, TPB, 0, stream>>>(
        out_item, agg_i, WTH + 2 * WSTRIDE, WTL + 2 * WSTRIDE, b2_uc, out_item, NI,
        out_user, agg_u, WTH + 3 * WSTRIDE, WTL + 3 * WSTRIDE, b2_iu, out_user, NU,
        mBlocksI, 0);
}